// Round 3
// baseline (198.914 us; speedup 1.0000x reference)
//
#include <hip/hip_runtime.h>
#include <hip/hip_bf16.h>

// Problem constants (from reference)
#define NN     16384   // nodes
#define HD     64      // hidden dim
#define BG     32      // graphs
#define NPG    512     // nodes per graph
#define NHEADS 8
#define DH     8
#define DEGMAX 40      // ELL width; deg ~ Poisson(16), P(>40) ~ 3e-8/node

// attn LDS geometry: per block 256 KV rows = 4 chunks x 64 rows, f32.
// Chunk stride 64*20+4 = 1284 words (R13-proven bank-clean geometry).
#define KVSTR  20
#define CSTR   (64 * KVSTR + 4)    // 1284

typedef __hip_bfloat16 bf16;

#if defined(__has_builtin)
#if __has_builtin(__builtin_amdgcn_exp2f)
#define EXP2F(x) __builtin_amdgcn_exp2f(x)
#else
#define EXP2F(x) exp2f(x)
#endif
#else
#define EXP2F(x) exp2f(x)
#endif

__device__ __forceinline__ float b2f(bf16 v) { return __bfloat162float(v); }

// Flag-steered input load: bf=1 -> buffer is bf16, bf=0 -> fp32.
__device__ __forceinline__ float ldf(const void* p, int i, int bf) {
  return bf ? __bfloat162float(((const bf16*)p)[i]) : ((const float*)p)[i];
}

__device__ __forceinline__ float wave_sum(float v) {
#pragma unroll
  for (int off = 32; off > 0; off >>= 1) v += __shfl_xor(v, off);
  return v;
}

__device__ __forceinline__ void unpack8(uint4 u, float* f) {
  f[0] = __uint_as_float(u.x << 16); f[1] = __uint_as_float(u.x & 0xffff0000u);
  f[2] = __uint_as_float(u.y << 16); f[3] = __uint_as_float(u.y & 0xffff0000u);
  f[4] = __uint_as_float(u.z << 16); f[5] = __uint_as_float(u.z & 0xffff0000u);
  f[6] = __uint_as_float(u.w << 16); f[7] = __uint_as_float(u.w & 0xffff0000u);
}

__device__ __forceinline__ unsigned short bfbits(float f) {
  bf16 b = __float2bfloat16(f);
  return *(unsigned short*)&b;
}

// Per-block dtype detection (bf16 vs fp32 inputs) — only k_build pays this
// (256 samples; bf16 scores ~256, fp32 ~51 — wide margin); publishes flag.
__device__ __forceinline__ int detect_bf(const unsigned short* xr, int tid, int nt) {
  __shared__ int s_cnt;
  if (tid == 0) s_cnt = 0;
  __syncthreads();
  int sane = 0;
  for (int i = tid; i < 256; i += nt) {
    int e = (xr[2 * i] >> 7) & 0xFF;
    sane += (e >= 100 && e <= 150) ? 1 : 0;
  }
  if (sane) atomicAdd(&s_cnt, sane);
  __syncthreads();
  return s_cnt > 180;
}

// Kernel 1: h = x @ w_gat (bf16 out); as_/ad_ logit halves; + fused ELL
// scatter; + publish dtype flag. 16 nodes/block (champion config —
// 32/block regressed in R20: doubles the edge-scatter trip count).
__global__ __launch_bounds__(256) void k_build(
    const void* __restrict__ x, const void* __restrict__ w,
    const void* __restrict__ asrc, const void* __restrict__ adst,
    const int* __restrict__ esrc, const int* __restrict__ edst, int E,
    int* __restrict__ cur, int* __restrict__ ell,
    bf16* __restrict__ h, float* __restrict__ as_, float* __restrict__ ad_,
    int* __restrict__ flagp)
{
  const int tid = threadIdx.x, lane = tid & 63, wid = tid >> 6;
  const int bf = detect_bf((const unsigned short*)x, tid, 256);
  if (tid == 0 && blockIdx.x == 0) *flagp = bf;
  __shared__ float wl[HD * HD];
  __shared__ float xr[4][HD];
  {
    for (int e = blockIdx.x * 256 + tid; e < E; e += gridDim.x * 256) {
      int d = edst[e];
      int k = atomicAdd(&cur[d], 1);
      if (k < DEGMAX) ell[d * DEGMAX + k] = esrc[e];
    }
  }
  for (int i = tid; i < HD * HD; i += 256) wl[i] = ldf(w, i, bf);
  const float av = ldf(asrc, lane, bf), dv_ = ldf(adst, lane, bf);
  __syncthreads();
#pragma unroll
  for (int r = 0; r < 4; ++r) {
    const int node = blockIdx.x * 16 + r * 4 + wid;
    xr[wid][lane] = ldf(x, node * HD + lane, bf);   // wave-local slot
    float hj = 0.f;
#pragma unroll
    for (int i = 0; i < HD; ++i) hj = fmaf(xr[wid][i], wl[i * HD + lane], hj);
    float pa = wave_sum(hj * av);
    float pd = wave_sum(hj * dv_);
    h[node * HD + lane] = __float2bfloat16(hj);
    if (lane == 0) { as_[node] = pa; ad_[node] = pd; }
  }
}

// Kernel 2: wave-per-node GAT gather (ELL) + bias + relu + residual + LN1 -> x1
// Batch-8 software pipeline: 8 independent neighbor loads in flight (MLP 8).
__global__ __launch_bounds__(256) void k_gather(
    const void* __restrict__ x, const int* __restrict__ cur,
    const int* __restrict__ ell, const float* __restrict__ as_,
    const float* __restrict__ ad_, const bf16* __restrict__ h,
    const void* __restrict__ bg, const void* __restrict__ g1,
    const void* __restrict__ b1, const int* __restrict__ dflag,
    bf16* __restrict__ x1)
{
  const int tid = threadIdx.x, lane = tid & 63, wid = tid >> 6;
  const int bf = *dflag;
  const int n = blockIdx.x * 4 + wid;
  const float adn = ad_[n];
  float e0 = as_[n] + adn;
  e0 = e0 > 0.f ? e0 : 0.2f * e0;
  float den = __expf(fminf(e0, 30.f));
  float num = den * b2f(h[n * HD + lane]);
  const int deg = min(cur[n], DEGMAX);
  const int* row = ell + n * DEGMAX;
  int i = 0;
  for (; i + 8 <= deg; i += 8) {
    int s[8];
#pragma unroll
    for (int k = 0; k < 8; ++k) s[k] = row[i + k];
    float a[8], hh[8];
#pragma unroll
    for (int k = 0; k < 8; ++k) a[k] = as_[s[k]];
#pragma unroll
    for (int k = 0; k < 8; ++k) hh[k] = b2f(h[s[k] * HD + lane]);
#pragma unroll
    for (int k = 0; k < 8; ++k) {
      float e = a[k] + adn;
      e = e > 0.f ? e : 0.2f * e;
      float p = __expf(fminf(e, 30.f));
      den += p;
      num = fmaf(p, hh[k], num);
    }
  }
  for (; i + 4 <= deg; i += 4) {
    int s0 = row[i], s1 = row[i + 1], s2 = row[i + 2], s3 = row[i + 3];
    float a0 = as_[s0], a1 = as_[s1], a2 = as_[s2], a3 = as_[s3];
    float h0 = b2f(h[s0 * HD + lane]), h1 = b2f(h[s1 * HD + lane]);
    float h2 = b2f(h[s2 * HD + lane]), h3 = b2f(h[s3 * HD + lane]);
    float e_0 = a0 + adn; e_0 = e_0 > 0.f ? e_0 : 0.2f * e_0;
    float e_1 = a1 + adn; e_1 = e_1 > 0.f ? e_1 : 0.2f * e_1;
    float e_2 = a2 + adn; e_2 = e_2 > 0.f ? e_2 : 0.2f * e_2;
    float e_3 = a3 + adn; e_3 = e_3 > 0.f ? e_3 : 0.2f * e_3;
    float p0 = __expf(fminf(e_0, 30.f)), p1 = __expf(fminf(e_1, 30.f));
    float p2 = __expf(fminf(e_2, 30.f)), p3 = __expf(fminf(e_3, 30.f));
    den += p0 + p1 + p2 + p3;
    num = fmaf(p0, h0, num); num = fmaf(p1, h1, num);
    num = fmaf(p2, h2, num); num = fmaf(p3, h3, num);
  }
  for (; i < deg; ++i) {
    int s = row[i];
    float e = as_[s] + adn;
    e = e > 0.f ? e : 0.2f * e;
    float p = __expf(fminf(e, 30.f));
    den += p;
    num = fmaf(p, b2f(h[s * HD + lane]), num);
  }
  float v = num / (den + 1e-16f) + ldf(bg, lane, bf);
  v = fmaxf(v, 0.f) + ldf(x, n * HD + lane, bf);
  float mu = wave_sum(v) * (1.f / 64.f);
  float dv = v - mu;
  float var = wave_sum(dv * dv) * (1.f / 64.f);
  float r = rsqrtf(var + 1e-5f);
  x1[n * HD + lane] =
      __float2bfloat16(dv * r * ldf(g1, lane, bf) + ldf(b1, lane, bf));
}

// Kernel 3: split-KV fused QKV + dense attention, 512 threads.
// R26: NO Q LDS buffer. Post-mortem R25: VGPR_Count=52 == exactly
// num[4][8]+den[4] (36) + K/V in flight (16) -> compiler was NOT keeping
// qv in registers; it re-read Q from LDS EVERY inner iteration (~12+
// ds_read/iter vs 4 modeled). LDS-pipe instruction issue (~50us/CU) is
// what pinned the kernel at 54us regardless of occupancy/prefetch.
// Fix: (a) thread t computes Q row t in registers; rows (t&~3)+i needed
// by thread t live in its own 4-lane shuffle cluster -> 32 one-time
// __shfl's, Q LDS deleted (-24.6 KB). (b) amdgpu_waves_per_eu(4,4) pins
// the allocator at the 128-VGPR budget so it cannot trade registers for
// occupancy again. Inner loop now truly 4 ds_read_b128/iter.
__global__ void __launch_bounds__(512)
__attribute__((amdgpu_waves_per_eu(4, 4))) k_attn13(
    const bf16* __restrict__ x1,
    const void* __restrict__ wq, const void* __restrict__ bq,
    const void* __restrict__ wk, const void* __restrict__ bk,
    const void* __restrict__ wv, const void* __restrict__ bv,
    const int* __restrict__ dflag,
    bf16* __restrict__ num_t, float* __restrict__ den_t)
{
  const int t = threadIdx.x;
  const int bf = *dflag;
  __shared__ float KV[4 * CSTR];     // 20.5 KB
  __shared__ float Wl[3][HD][DH];    // 6 KB
  __shared__ float bl[3][DH];
  const int bid = blockIdx.x;
  const int g = bid >> 4, hd = (bid >> 1) & 7, half = bid & 1;
  {
    // 512 threads, 512 (i,j) cells per matrix: one cell each.
    int i = t >> 3, j = t & 7;
    int col = hd * DH + j;
    Wl[0][i][j] = ldf(wq, i * HD + col, bf);
    Wl[1][i][j] = ldf(wk, i * HD + col, bf);
    Wl[2][i][j] = ldf(wv, i * HD + col, bf);
    if (t < DH) {
      bl[0][t] = ldf(bq, hd * DH + t, bf);
      bl[1][t] = ldf(bk, hd * DH + t, bf);
      bl[2][t] = ldf(bv, hd * DH + t, bf);
    }
  }
  __syncthreads();
  // qscale = (1/sqrt(8)) * log2(e): softmax via exp2.
  const float qscale = 0.3535533905932738f * 1.4426950408889634f;
  {
    // ---- K (waves 0-3) or V (waves 4-7) projection for local row t&255 ----
    const int r = t & 255;
    const int m = (t < 256) ? 1 : 2;   // wave-uniform: no divergence
    const uint4* xk4 = (const uint4*)(x1 + (size_t)(g * NPG + half * 256 + r) * HD);
    float acc[DH];
#pragma unroll
    for (int j = 0; j < DH; ++j) acc[j] = bl[m][j];
#pragma unroll
    for (int blk = 0; blk < 8; ++blk) {
      float xv[8];
      unpack8(xk4[blk], xv);
      const int ib = blk * 8;
#pragma unroll
      for (int ii = 0; ii < 8; ++ii)
#pragma unroll
        for (int j = 0; j < DH; ++j)
          acc[j] = fmaf(xv[ii], Wl[m][ib + ii][j], acc[j]);
    }
    float* kvrow = KV + (r >> 6) * CSTR + (r & 63) * KVSTR + (t < 256 ? 0 : 8);
    *(float4*)(kvrow + 0) = make_float4(acc[0], acc[1], acc[2], acc[3]);
    *(float4*)(kvrow + 4) = make_float4(acc[4], acc[5], acc[6], acc[7]);
  }
  // ---- Q projection: row t, REGISTERS ONLY (no LDS round-trip) ----
  float qa[DH];
  {
    const uint4* xa4 = (const uint4*)(x1 + (size_t)(g * NPG + t) * HD);
#pragma unroll
    for (int j = 0; j < DH; ++j) qa[j] = bl[0][j];
#pragma unroll
    for (int blk = 0; blk < 8; ++blk) {
      float xv[8];
      unpack8(xa4[blk], xv);
      const int ib = blk * 8;
#pragma unroll
      for (int ii = 0; ii < 8; ++ii)
#pragma unroll
        for (int j = 0; j < DH; ++j)
          qa[j] = fmaf(xv[ii], Wl[0][ib + ii][j], qa[j]);
    }
#pragma unroll
    for (int j = 0; j < DH; ++j) qa[j] *= qscale;
  }
  __syncthreads();   // KV LDS ready
  // ---- redistribute Q inside each 4-lane cluster: thread t needs rows
  // (t&~3)+i, computed by lanes (lane&~3)+i of the SAME wave. ----
  const int lane = t & 63;
  const int base = lane & ~3;
  float qv[4][DH];
#pragma unroll
  for (int i = 0; i < 4; ++i)
#pragma unroll
    for (int j = 0; j < DH; ++j)
      qv[i][j] = __shfl(qa[j], base + i, 64);
  // ---- attention: 4 queries per thread over a 64-row chunk ----
  const int qg = t >> 2, c = t & 3;   // qg in [0,128): queries qg*4 .. qg*4+3
  float den[4], num[4][DH];
#pragma unroll
  for (int i = 0; i < 4; ++i) {
    den[i] = 0.f;
#pragma unroll
    for (int j = 0; j < DH; ++j) num[i][j] = 0.f;
  }
  const float* kvc = KV + c * CSTR;
#pragma unroll 4
  for (int jj = 0; jj < 64; ++jj) {
    const float4* kv4 = (const float4*)(kvc + jj * KVSTR);
    float4 k0 = kv4[0], k1 = kv4[1], v0 = kv4[2], v1 = kv4[3];
#pragma unroll
    for (int i = 0; i < 4; ++i) {
      float s = qv[i][0] * k0.x;
      s = fmaf(qv[i][1], k0.y, s); s = fmaf(qv[i][2], k0.z, s);
      s = fmaf(qv[i][3], k0.w, s); s = fmaf(qv[i][4], k1.x, s);
      s = fmaf(qv[i][5], k1.y, s); s = fmaf(qv[i][6], k1.z, s);
      s = fmaf(qv[i][7], k1.w, s);
      float p = EXP2F(s);   // q pre-scaled by log2e/sqrt(DH)
      den[i] += p;
      num[i][0] = fmaf(p, v0.x, num[i][0]); num[i][1] = fmaf(p, v0.y, num[i][1]);
      num[i][2] = fmaf(p, v0.z, num[i][2]); num[i][3] = fmaf(p, v0.w, num[i][3]);
      num[i][4] = fmaf(p, v1.x, num[i][4]); num[i][5] = fmaf(p, v1.y, num[i][5]);
      num[i][6] = fmaf(p, v1.z, num[i][6]); num[i][7] = fmaf(p, v1.w, num[i][7]);
    }
  }
  // merge the 4 chunk-lanes (butterfly over c bits 1,2)
#pragma unroll
  for (int st = 1; st <= 2; st <<= 1) {
#pragma unroll
    for (int i = 0; i < 4; ++i) {
      den[i] += __shfl_xor(den[i], st);
#pragma unroll
      for (int j = 0; j < DH; ++j) num[i][j] += __shfl_xor(num[i][j], st);
    }
  }
  // lane c writes query qg*4+c UNNORMALIZED (one query per lane).
  const int plane = half * 8 + hd;
  float dsel = 0.f, rsel[DH];
#pragma unroll
  for (int j = 0; j < DH; ++j) rsel[j] = 0.f;
#pragma unroll
  for (int i = 0; i < 4; ++i) {
    if (c == i) {
      dsel = den[i];
#pragma unroll
      for (int j = 0; j < DH; ++j) rsel[j] = num[i][j];
    }
  }
  const int qrow = qg * 4 + c;
  union { uint4 u4; unsigned short us[8]; } pk;
#pragma unroll
  for (int j = 0; j < DH; ++j) pk.us[j] = bfbits(rsel[j]);
  *(uint4*)(num_t + ((size_t)plane * NN + g * NPG + qrow) * 8) = pk.u4;
  den_t[(size_t)plane * NN + g * NPG + qrow] = dsel;
}

// Kernel 4: merge attn halves -> o; y = relu(o @ wo + bo);
// out = LN(x1 + y; g2, b2). 32 nodes/block (isolated de-confound of R20:
// halves the 16 KB wo-staging traffic; no atomics/grid-stride coupling).
__global__ __launch_bounds__(256) void k_out(
    const bf16* __restrict__ num_t, const float* __restrict__ den_t,
    const bf16* __restrict__ x1,
    const void* __restrict__ wo, const void* __restrict__ bo,
    const void* __restrict__ g2, const void* __restrict__ b2,
    const int* __restrict__ dflag, void* __restrict__ out)
{
  const int tid = threadIdx.x, lane = tid & 63, wid = tid >> 6;
  const int bf = *dflag;
  __shared__ float wl[HD * HD];
  __shared__ float orow[4][HD];
  for (int i = tid; i < HD * HD; i += 256) wl[i] = ldf(wo, i, bf);
  const float bov = ldf(bo, lane, bf);
  const float g2v = ldf(g2, lane, bf);
  const float b2v = ldf(b2, lane, bf);
  const int hdp = lane >> 3, jp = lane & 7;
  __syncthreads();
#pragma unroll
  for (int r = 0; r < 8; ++r) {
    const int node = blockIdx.x * 32 + r * 4 + wid;
    {
      float nm = b2f(num_t[((size_t)hdp * NN + node) * 8 + jp]) +
                 b2f(num_t[((size_t)(8 + hdp) * NN + node) * 8 + jp]);
      float dn = den_t[(size_t)hdp * NN + node] +
                 den_t[(size_t)(8 + hdp) * NN + node];
      orow[wid][lane] = nm / dn;   // wave-local slot
    }
    float y = bov;
#pragma unroll
    for (int i = 0; i < HD; ++i) y = fmaf(orow[wid][i], wl[i * HD + lane], y);
    float tt = b2f(x1[node * HD + lane]) + fmaxf(y, 0.f);
    float mu = wave_sum(tt) * (1.f / 64.f);
    float dv = tt - mu;
    float var = wave_sum(dv * dv) * (1.f / 64.f);
    float rr = rsqrtf(var + 1e-5f);
    float res = dv * rr * g2v + b2v;
    if (bf) ((bf16*)out)[node * HD + lane] = __float2bfloat16(res);
    else    ((float*)out)[node * HD + lane] = res;
  }
}

extern "C" void kernel_launch(void* const* d_in, const int* in_sizes, int n_in,
                              void* d_out, int out_size, void* d_ws, size_t ws_size,
                              hipStream_t stream)
{
  const void* x    = d_in[0];
  const void* wgat = d_in[1];
  const void* asrc = d_in[2];
  const void* adst = d_in[3];
  const void* bgat = d_in[4];
  const void* g1   = d_in[5];
  const void* b1   = d_in[6];
  const void* wq   = d_in[7];
  const void* bq   = d_in[8];
  const void* wk   = d_in[9];
  const void* bk   = d_in[10];
  const void* wv   = d_in[11];
  const void* bv   = d_in[12];
  const void* wo   = d_in[13];
  const void* bo   = d_in[14];
  const void* g2   = d_in[15];
  const void* b2   = d_in[16];
  const int*  ei   = (const int*)d_in[17];
  const int E = in_sizes[17] / 2;
  const int* esrc = ei;
  const int* edst = ei + E;

  // Workspace (~7.2 MiB):
  //   [0, 2M):      bf16 x1
  //   [2M, 4.62M):  ell (NN*DEGMAX int)    } dead after k_gather;
  //   [4.62M,6.62M):bf16 h                 } k_attn13 overwrites:
  //   [2M, 6M):     bf16 num_t (16 planes * NN * 8)
  //   [6M, 7M):     f32 den_t (16 planes * NN)
  //   [7M, ...):    as_, ad_ (NN f32 each), cur (NN int), flag
  char* W = (char*)d_ws;
  bf16*  x1b   = (bf16*)W;
  int*   ell   = (int*)(W + (size_t)(2 << 20));
  bf16*  hb    = (bf16*)(W + (size_t)(2 << 20) + (size_t)NN * DEGMAX * 4);
  bf16*  num_t = (bf16*)(W + (size_t)(2 << 20));
  float* den_t = (float*)(W + (size_t)(6 << 20));
  float* as_   = (float*)(W + (size_t)(7 << 20));
  float* ad_   = as_ + NN;
  int*   cur   = (int*)(ad_ + NN);
  int*   flag  = cur + NN;

  hipMemsetAsync(cur, 0, NN * sizeof(int), stream);
  k_build  <<<NN / 16, 256, 0, stream>>>(x, wgat, asrc, adst, esrc, edst, E,
                                         cur, ell, hb, as_, ad_, flag);
  k_gather <<<NN / 4, 256, 0, stream>>>(x, cur, ell, as_, ad_, hb,
                                        bgat, g1, b1, flag, x1b);
  k_attn13 <<<BG * NHEADS * 2, 512, 0, stream>>>(x1b, wq, bq, wk, bk, wv, bv,
                                                 flag, num_t, den_t);
  k_out    <<<NN / 32, 256, 0, stream>>>(num_t, den_t, x1b, wo, bo, g2, b2,
                                         flag, d_out);
}

// Round 5
// 194.905 us; speedup vs baseline: 1.0206x; 1.0206x over previous
//
#include <hip/hip_runtime.h>
#include <hip/hip_bf16.h>

// Problem constants (from reference)
#define NN     16384   // nodes
#define HD     64      // hidden dim
#define BG     32      // graphs
#define NPG    512     // nodes per graph
#define NHEADS 8
#define DH     8
#define DEGMAX 40      // ELL width; deg ~ Poisson(16), P(>40) ~ 3e-8/node

// attn LDS geometry: per block 256 KV rows = 4 chunks x 64 rows, f32.
// Chunk stride 64*20+4 = 1284 words (R13-proven bank-clean geometry).
#define KVSTR  20
#define CSTR   (64 * KVSTR + 4)    // 1284

typedef __hip_bfloat16 bf16;

#if defined(__has_builtin)
#if __has_builtin(__builtin_amdgcn_exp2f)
#define EXP2F(x) __builtin_amdgcn_exp2f(x)
#else
#define EXP2F(x) exp2f(x)
#endif
#else
#define EXP2F(x) exp2f(x)
#endif

__device__ __forceinline__ float b2f(bf16 v) { return __bfloat162float(v); }

// Flag-steered input load: bf=1 -> buffer is bf16, bf=0 -> fp32.
__device__ __forceinline__ float ldf(const void* p, int i, int bf) {
  return bf ? __bfloat162float(((const bf16*)p)[i]) : ((const float*)p)[i];
}

__device__ __forceinline__ float wave_sum(float v) {
#pragma unroll
  for (int off = 32; off > 0; off >>= 1) v += __shfl_xor(v, off);
  return v;
}

__device__ __forceinline__ void unpack8(uint4 u, float* f) {
  f[0] = __uint_as_float(u.x << 16); f[1] = __uint_as_float(u.x & 0xffff0000u);
  f[2] = __uint_as_float(u.y << 16); f[3] = __uint_as_float(u.y & 0xffff0000u);
  f[4] = __uint_as_float(u.z << 16); f[5] = __uint_as_float(u.z & 0xffff0000u);
  f[6] = __uint_as_float(u.w << 16); f[7] = __uint_as_float(u.w & 0xffff0000u);
}

__device__ __forceinline__ unsigned short bfbits(float f) {
  bf16 b = __float2bfloat16(f);
  return *(unsigned short*)&b;
}

// Per-block dtype detection (bf16 vs fp32 inputs) — only k_build pays this
// (256 samples; bf16 scores ~256, fp32 ~51 — wide margin); publishes flag.
__device__ __forceinline__ int detect_bf(const unsigned short* xr, int tid, int nt) {
  __shared__ int s_cnt;
  if (tid == 0) s_cnt = 0;
  __syncthreads();
  int sane = 0;
  for (int i = tid; i < 256; i += nt) {
    int e = (xr[2 * i] >> 7) & 0xFF;
    sane += (e >= 100 && e <= 150) ? 1 : 0;
  }
  if (sane) atomicAdd(&s_cnt, sane);
  __syncthreads();
  return s_cnt > 180;
}

// Kernel 1: h = x @ w_gat (bf16 out); as_/ad_ logit halves; + fused ELL
// scatter; + publish dtype flag. 16 nodes/block (champion config —
// 32/block regressed in R20: doubles the edge-scatter trip count).
__global__ __launch_bounds__(256) void k_build(
    const void* __restrict__ x, const void* __restrict__ w,
    const void* __restrict__ asrc, const void* __restrict__ adst,
    const int* __restrict__ esrc, const int* __restrict__ edst, int E,
    int* __restrict__ cur, int* __restrict__ ell,
    bf16* __restrict__ h, float* __restrict__ as_, float* __restrict__ ad_,
    int* __restrict__ flagp)
{
  const int tid = threadIdx.x, lane = tid & 63, wid = tid >> 6;
  const int bf = detect_bf((const unsigned short*)x, tid, 256);
  if (tid == 0 && blockIdx.x == 0) *flagp = bf;
  __shared__ float wl[HD * HD];
  __shared__ float xr[4][HD];
  {
    for (int e = blockIdx.x * 256 + tid; e < E; e += gridDim.x * 256) {
      int d = edst[e];
      int k = atomicAdd(&cur[d], 1);
      if (k < DEGMAX) ell[d * DEGMAX + k] = esrc[e];
    }
  }
  for (int i = tid; i < HD * HD; i += 256) wl[i] = ldf(w, i, bf);
  const float av = ldf(asrc, lane, bf), dv_ = ldf(adst, lane, bf);
  __syncthreads();
#pragma unroll
  for (int r = 0; r < 4; ++r) {
    const int node = blockIdx.x * 16 + r * 4 + wid;
    xr[wid][lane] = ldf(x, node * HD + lane, bf);   // wave-local slot
    float hj = 0.f;
#pragma unroll
    for (int i = 0; i < HD; ++i) hj = fmaf(xr[wid][i], wl[i * HD + lane], hj);
    float pa = wave_sum(hj * av);
    float pd = wave_sum(hj * dv_);
    h[node * HD + lane] = __float2bfloat16(hj);
    if (lane == 0) { as_[node] = pa; ad_[node] = pd; }
  }
}

// Kernel 2: wave-per-node GAT gather (ELL) + bias + relu + residual + LN1 -> x1
// Batch-8 software pipeline: 8 independent neighbor loads in flight (MLP 8).
__global__ __launch_bounds__(256) void k_gather(
    const void* __restrict__ x, const int* __restrict__ cur,
    const int* __restrict__ ell, const float* __restrict__ as_,
    const float* __restrict__ ad_, const bf16* __restrict__ h,
    const void* __restrict__ bg, const void* __restrict__ g1,
    const void* __restrict__ b1, const int* __restrict__ dflag,
    bf16* __restrict__ x1)
{
  const int tid = threadIdx.x, lane = tid & 63, wid = tid >> 6;
  const int bf = *dflag;
  const int n = blockIdx.x * 4 + wid;
  const float adn = ad_[n];
  float e0 = as_[n] + adn;
  e0 = e0 > 0.f ? e0 : 0.2f * e0;
  float den = __expf(fminf(e0, 30.f));
  float num = den * b2f(h[n * HD + lane]);
  const int deg = min(cur[n], DEGMAX);
  const int* row = ell + n * DEGMAX;
  int i = 0;
  for (; i + 8 <= deg; i += 8) {
    int s[8];
#pragma unroll
    for (int k = 0; k < 8; ++k) s[k] = row[i + k];
    float a[8], hh[8];
#pragma unroll
    for (int k = 0; k < 8; ++k) a[k] = as_[s[k]];
#pragma unroll
    for (int k = 0; k < 8; ++k) hh[k] = b2f(h[s[k] * HD + lane]);
#pragma unroll
    for (int k = 0; k < 8; ++k) {
      float e = a[k] + adn;
      e = e > 0.f ? e : 0.2f * e;
      float p = __expf(fminf(e, 30.f));
      den += p;
      num = fmaf(p, hh[k], num);
    }
  }
  for (; i + 4 <= deg; i += 4) {
    int s0 = row[i], s1 = row[i + 1], s2 = row[i + 2], s3 = row[i + 3];
    float a0 = as_[s0], a1 = as_[s1], a2 = as_[s2], a3 = as_[s3];
    float h0 = b2f(h[s0 * HD + lane]), h1 = b2f(h[s1 * HD + lane]);
    float h2 = b2f(h[s2 * HD + lane]), h3 = b2f(h[s3 * HD + lane]);
    float e_0 = a0 + adn; e_0 = e_0 > 0.f ? e_0 : 0.2f * e_0;
    float e_1 = a1 + adn; e_1 = e_1 > 0.f ? e_1 : 0.2f * e_1;
    float e_2 = a2 + adn; e_2 = e_2 > 0.f ? e_2 : 0.2f * e_2;
    float e_3 = a3 + adn; e_3 = e_3 > 0.f ? e_3 : 0.2f * e_3;
    float p0 = __expf(fminf(e_0, 30.f)), p1 = __expf(fminf(e_1, 30.f));
    float p2 = __expf(fminf(e_2, 30.f)), p3 = __expf(fminf(e_3, 30.f));
    den += p0 + p1 + p2 + p3;
    num = fmaf(p0, h0, num); num = fmaf(p1, h1, num);
    num = fmaf(p2, h2, num); num = fmaf(p3, h3, num);
  }
  for (; i < deg; ++i) {
    int s = row[i];
    float e = as_[s] + adn;
    e = e > 0.f ? e : 0.2f * e;
    float p = __expf(fminf(e, 30.f));
    den += p;
    num = fmaf(p, b2f(h[s * HD + lane]), num);
  }
  float v = num / (den + 1e-16f) + ldf(bg, lane, bf);
  v = fmaxf(v, 0.f) + ldf(x, n * HD + lane, bf);
  float mu = wave_sum(v) * (1.f / 64.f);
  float dv = v - mu;
  float var = wave_sum(dv * dv) * (1.f / 64.f);
  float r = rsqrtf(var + 1e-5f);
  x1[n * HD + lane] =
      __float2bfloat16(dv * r * ldf(g1, lane, bf) + ldf(b1, lane, bf));
}

// Kernel 3: split-KV fused QKV + dense attention, 512 threads.
// R27 (resubmitted after R4 GPU-acquisition timeout — never measured):
// R26 structure (no Q LDS; Q in regs via 4-lane-cluster shuffles;
// 4 ds_read_b128/iter) with __launch_bounds__(512, 4) for the register
// budget. Post-mortem R26: amdgpu_waves_per_eu(4,4) was silently ignored
// -> allocator targeted 8 waves/EU (VGPR=64), qv+num+kv (84+) could not
// fit, and with no LDS Q to rematerialize from it spilled to SCRATCH
// (WRITE_SIZE 5120->17408 KB, +4.5us). launch_bounds(512,4) is the
// proven path to a 128-VGPR budget (R24/R25 allocated under it); live
// state ~100 regs now fits. Falsifiable: VGPR must rise to ~96-112 and
// WRITE_SIZE return to 5120; else allocator theory is dead -> MFMA.
__global__ __launch_bounds__(512, 4) void k_attn13(
    const bf16* __restrict__ x1,
    const void* __restrict__ wq, const void* __restrict__ bq,
    const void* __restrict__ wk, const void* __restrict__ bk,
    const void* __restrict__ wv, const void* __restrict__ bv,
    const int* __restrict__ dflag,
    bf16* __restrict__ num_t, float* __restrict__ den_t)
{
  const int t = threadIdx.x;
  const int bf = *dflag;
  __shared__ float KV[4 * CSTR];     // 20.5 KB
  __shared__ float Wl[3][HD][DH];    // 6 KB
  __shared__ float bl[3][DH];
  const int bid = blockIdx.x;
  const int g = bid >> 4, hd = (bid >> 1) & 7, half = bid & 1;
  {
    // 512 threads, 512 (i,j) cells per matrix: one cell each.
    int i = t >> 3, j = t & 7;
    int col = hd * DH + j;
    Wl[0][i][j] = ldf(wq, i * HD + col, bf);
    Wl[1][i][j] = ldf(wk, i * HD + col, bf);
    Wl[2][i][j] = ldf(wv, i * HD + col, bf);
    if (t < DH) {
      bl[0][t] = ldf(bq, hd * DH + t, bf);
      bl[1][t] = ldf(bk, hd * DH + t, bf);
      bl[2][t] = ldf(bv, hd * DH + t, bf);
    }
  }
  __syncthreads();
  // qscale = (1/sqrt(8)) * log2(e): softmax via exp2.
  const float qscale = 0.3535533905932738f * 1.4426950408889634f;
  {
    // ---- K (waves 0-3) or V (waves 4-7) projection for local row t&255 ----
    const int r = t & 255;
    const int m = (t < 256) ? 1 : 2;   // wave-uniform: no divergence
    const uint4* xk4 = (const uint4*)(x1 + (size_t)(g * NPG + half * 256 + r) * HD);
    float acc[DH];
#pragma unroll
    for (int j = 0; j < DH; ++j) acc[j] = bl[m][j];
#pragma unroll
    for (int blk = 0; blk < 8; ++blk) {
      float xv[8];
      unpack8(xk4[blk], xv);
      const int ib = blk * 8;
#pragma unroll
      for (int ii = 0; ii < 8; ++ii)
#pragma unroll
        for (int j = 0; j < DH; ++j)
          acc[j] = fmaf(xv[ii], Wl[m][ib + ii][j], acc[j]);
    }
    float* kvrow = KV + (r >> 6) * CSTR + (r & 63) * KVSTR + (t < 256 ? 0 : 8);
    *(float4*)(kvrow + 0) = make_float4(acc[0], acc[1], acc[2], acc[3]);
    *(float4*)(kvrow + 4) = make_float4(acc[4], acc[5], acc[6], acc[7]);
  }
  // ---- Q projection: row t, REGISTERS ONLY (no LDS round-trip) ----
  float qa[DH];
  {
    const uint4* xa4 = (const uint4*)(x1 + (size_t)(g * NPG + t) * HD);
#pragma unroll
    for (int j = 0; j < DH; ++j) qa[j] = bl[0][j];
#pragma unroll
    for (int blk = 0; blk < 8; ++blk) {
      float xv[8];
      unpack8(xa4[blk], xv);
      const int ib = blk * 8;
#pragma unroll
      for (int ii = 0; ii < 8; ++ii)
#pragma unroll
        for (int j = 0; j < DH; ++j)
          qa[j] = fmaf(xv[ii], Wl[0][ib + ii][j], qa[j]);
    }
#pragma unroll
    for (int j = 0; j < DH; ++j) qa[j] *= qscale;
  }
  __syncthreads();   // KV LDS ready
  // ---- redistribute Q inside each 4-lane cluster: thread t needs rows
  // (t&~3)+i, computed by lanes (lane&~3)+i of the SAME wave. ----
  const int lane = t & 63;
  const int base = lane & ~3;
  float qv[4][DH];
#pragma unroll
  for (int i = 0; i < 4; ++i)
#pragma unroll
    for (int j = 0; j < DH; ++j)
      qv[i][j] = __shfl(qa[j], base + i, 64);
  // ---- attention: 4 queries per thread over a 64-row chunk ----
  const int qg = t >> 2, c = t & 3;   // qg in [0,128): queries qg*4 .. qg*4+3
  float den[4], num[4][DH];
#pragma unroll
  for (int i = 0; i < 4; ++i) {
    den[i] = 0.f;
#pragma unroll
    for (int j = 0; j < DH; ++j) num[i][j] = 0.f;
  }
  const float* kvc = KV + c * CSTR;
#pragma unroll 4
  for (int jj = 0; jj < 64; ++jj) {
    const float4* kv4 = (const float4*)(kvc + jj * KVSTR);
    float4 k0 = kv4[0], k1 = kv4[1], v0 = kv4[2], v1 = kv4[3];
#pragma unroll
    for (int i = 0; i < 4; ++i) {
      float s = qv[i][0] * k0.x;
      s = fmaf(qv[i][1], k0.y, s); s = fmaf(qv[i][2], k0.z, s);
      s = fmaf(qv[i][3], k0.w, s); s = fmaf(qv[i][4], k1.x, s);
      s = fmaf(qv[i][5], k1.y, s); s = fmaf(qv[i][6], k1.z, s);
      s = fmaf(qv[i][7], k1.w, s);
      float p = EXP2F(s);   // q pre-scaled by log2e/sqrt(DH)
      den[i] += p;
      num[i][0] = fmaf(p, v0.x, num[i][0]); num[i][1] = fmaf(p, v0.y, num[i][1]);
      num[i][2] = fmaf(p, v0.z, num[i][2]); num[i][3] = fmaf(p, v0.w, num[i][3]);
      num[i][4] = fmaf(p, v1.x, num[i][4]); num[i][5] = fmaf(p, v1.y, num[i][5]);
      num[i][6] = fmaf(p, v1.z, num[i][6]); num[i][7] = fmaf(p, v1.w, num[i][7]);
    }
  }
  // merge the 4 chunk-lanes (butterfly over c bits 1,2)
#pragma unroll
  for (int st = 1; st <= 2; st <<= 1) {
#pragma unroll
    for (int i = 0; i < 4; ++i) {
      den[i] += __shfl_xor(den[i], st);
#pragma unroll
      for (int j = 0; j < DH; ++j) num[i][j] += __shfl_xor(num[i][j], st);
    }
  }
  // lane c writes query qg*4+c UNNORMALIZED (one query per lane).
  const int plane = half * 8 + hd;
  float dsel = 0.f, rsel[DH];
#pragma unroll
  for (int j = 0; j < DH; ++j) rsel[j] = 0.f;
#pragma unroll
  for (int i = 0; i < 4; ++i) {
    if (c == i) {
      dsel = den[i];
#pragma unroll
      for (int j = 0; j < DH; ++j) rsel[j] = num[i][j];
    }
  }
  const int qrow = qg * 4 + c;
  union { uint4 u4; unsigned short us[8]; } pk;
#pragma unroll
  for (int j = 0; j < DH; ++j) pk.us[j] = bfbits(rsel[j]);
  *(uint4*)(num_t + ((size_t)plane * NN + g * NPG + qrow) * 8) = pk.u4;
  den_t[(size_t)plane * NN + g * NPG + qrow] = dsel;
}

// Kernel 4: merge attn halves -> o; y = relu(o @ wo + bo);
// out = LN(x1 + y; g2, b2). 32 nodes/block (isolated de-confound of R20:
// halves the 16 KB wo-staging traffic; no atomics/grid-stride coupling).
__global__ __launch_bounds__(256) void k_out(
    const bf16* __restrict__ num_t, const float* __restrict__ den_t,
    const bf16* __restrict__ x1,
    const void* __restrict__ wo, const void* __restrict__ bo,
    const void* __restrict__ g2, const void* __restrict__ b2,
    const int* __restrict__ dflag, void* __restrict__ out)
{
  const int tid = threadIdx.x, lane = tid & 63, wid = tid >> 6;
  const int bf = *dflag;
  __shared__ float wl[HD * HD];
  __shared__ float orow[4][HD];
  for (int i = tid; i < HD * HD; i += 256) wl[i] = ldf(wo, i, bf);
  const float bov = ldf(bo, lane, bf);
  const float g2v = ldf(g2, lane, bf);
  const float b2v = ldf(b2, lane, bf);
  const int hdp = lane >> 3, jp = lane & 7;
  __syncthreads();
#pragma unroll
  for (int r = 0; r < 8; ++r) {
    const int node = blockIdx.x * 32 + r * 4 + wid;
    {
      float nm = b2f(num_t[((size_t)hdp * NN + node) * 8 + jp]) +
                 b2f(num_t[((size_t)(8 + hdp) * NN + node) * 8 + jp]);
      float dn = den_t[(size_t)hdp * NN + node] +
                 den_t[(size_t)(8 + hdp) * NN + node];
      orow[wid][lane] = nm / dn;   // wave-local slot
    }
    float y = bov;
#pragma unroll
    for (int i = 0; i < HD; ++i) y = fmaf(orow[wid][i], wl[i * HD + lane], y);
    float tt = b2f(x1[node * HD + lane]) + fmaxf(y, 0.f);
    float mu = wave_sum(tt) * (1.f / 64.f);
    float dv = tt - mu;
    float var = wave_sum(dv * dv) * (1.f / 64.f);
    float rr = rsqrtf(var + 1e-5f);
    float res = dv * rr * g2v + b2v;
    if (bf) ((bf16*)out)[node * HD + lane] = __float2bfloat16(res);
    else    ((float*)out)[node * HD + lane] = res;
  }
}

extern "C" void kernel_launch(void* const* d_in, const int* in_sizes, int n_in,
                              void* d_out, int out_size, void* d_ws, size_t ws_size,
                              hipStream_t stream)
{
  const void* x    = d_in[0];
  const void* wgat = d_in[1];
  const void* asrc = d_in[2];
  const void* adst = d_in[3];
  const void* bgat = d_in[4];
  const void* g1   = d_in[5];
  const void* b1   = d_in[6];
  const void* wq   = d_in[7];
  const void* bq   = d_in[8];
  const void* wk   = d_in[9];
  const void* bk   = d_in[10];
  const void* wv   = d_in[11];
  const void* bv   = d_in[12];
  const void* wo   = d_in[13];
  const void* bo   = d_in[14];
  const void* g2   = d_in[15];
  const void* b2   = d_in[16];
  const int*  ei   = (const int*)d_in[17];
  const int E = in_sizes[17] / 2;
  const int* esrc = ei;
  const int* edst = ei + E;

  // Workspace (~7.2 MiB):
  //   [0, 2M):      bf16 x1
  //   [2M, 4.62M):  ell (NN*DEGMAX int)    } dead after k_gather;
  //   [4.62M,6.62M):bf16 h                 } k_attn13 overwrites:
  //   [2M, 6M):     bf16 num_t (16 planes * NN * 8)
  //   [6M, 7M):     f32 den_t (16 planes * NN)
  //   [7M, ...):    as_, ad_ (NN f32 each), cur (NN int), flag
  char* W = (char*)d_ws;
  bf16*  x1b   = (bf16*)W;
  int*   ell   = (int*)(W + (size_t)(2 << 20));
  bf16*  hb    = (bf16*)(W + (size_t)(2 << 20) + (size_t)NN * DEGMAX * 4);
  bf16*  num_t = (bf16*)(W + (size_t)(2 << 20));
  float* den_t = (float*)(W + (size_t)(6 << 20));
  float* as_   = (float*)(W + (size_t)(7 << 20));
  float* ad_   = as_ + NN;
  int*   cur   = (int*)(ad_ + NN);
  int*   flag  = cur + NN;

  hipMemsetAsync(cur, 0, NN * sizeof(int), stream);
  k_build  <<<NN / 16, 256, 0, stream>>>(x, wgat, asrc, adst, esrc, edst, E,
                                         cur, ell, hb, as_, ad_, flag);
  k_gather <<<NN / 4, 256, 0, stream>>>(x, cur, ell, as_, ad_, hb,
                                        bgat, g1, b1, flag, x1b);
  k_attn13 <<<BG * NHEADS * 2, 512, 0, stream>>>(x1b, wq, bq, wk, bk, wv, bv,
                                                 flag, num_t, den_t);
  k_out    <<<NN / 32, 256, 0, stream>>>(num_t, den_t, x1b, wo, bo, g2, b2,
                                         flag, d_out);
}

// Round 8
// 193.722 us; speedup vs baseline: 1.0268x; 1.0061x over previous
//
#include <hip/hip_runtime.h>
#include <hip/hip_bf16.h>
#include <hip/hip_fp16.h>

// Problem constants (from reference)
#define NN     16384   // nodes
#define HD     64      // hidden dim
#define BG     32      // graphs
#define NPG    512     // nodes per graph
#define NHEADS 8
#define DH     8
#define DEGMAX 40      // ELL width; deg ~ Poisson(16), P(>40) ~ 3e-8/node

// R29 attn LDS geometry: K/V packed f16. Per row: K 8×f16 (16B) + V 8×f16
// (16B) = 8 u32 words. Chunk = 64 rows (512 words) + 4-word pad so the four
// chunks start 4 banks apart -> the 4 distinct 16B read-lines per wave
// instruction occupy disjoint bank quads (conflict-free reads).
#define KCH  (64 * 8 + 4)   // 516 words per chunk

typedef __hip_bfloat16 bf16;

#if defined(__has_builtin)
#if __has_builtin(__builtin_amdgcn_exp2f)
#define EXP2F(x) __builtin_amdgcn_exp2f(x)
#else
#define EXP2F(x) exp2f(x)
#endif
#if __has_builtin(__builtin_amdgcn_fdot2)
#define HAS_FDOT2 1
#endif
#else
#define EXP2F(x) exp2f(x)
#endif

#ifdef HAS_FDOT2
typedef _Float16 hvec2 __attribute__((ext_vector_type(2)));
#endif

// dot2 on two packed-f16 u32 words, f32 accumulate. Bitcast is free; the
// fallback is plain f32 math via hip_fp16 conversions (no exotic codegen).
__device__ __forceinline__ float fdot2u(unsigned a, unsigned b, float c) {
#ifdef HAS_FDOT2
  union { unsigned u; hvec2 v; } x, y;
  x.u = a; y.u = b;
  return __builtin_amdgcn_fdot2(x.v, y.v, c, false);
#else
  union { unsigned u; __half2 h; } x, y;
  x.u = a; y.u = b;
  return fmaf(__low2float(x.h), __low2float(y.h),
              fmaf(__high2float(x.h), __high2float(y.h), c));
#endif
}

__device__ __forceinline__ float b2f(bf16 v) { return __bfloat162float(v); }

// Flag-steered input load: bf=1 -> buffer is bf16, bf=0 -> fp32.
__device__ __forceinline__ float ldf(const void* p, int i, int bf) {
  return bf ? __bfloat162float(((const bf16*)p)[i]) : ((const float*)p)[i];
}

__device__ __forceinline__ float wave_sum(float v) {
#pragma unroll
  for (int off = 32; off > 0; off >>= 1) v += __shfl_xor(v, off);
  return v;
}

__device__ __forceinline__ void unpack8(uint4 u, float* f) {
  f[0] = __uint_as_float(u.x << 16); f[1] = __uint_as_float(u.x & 0xffff0000u);
  f[2] = __uint_as_float(u.y << 16); f[3] = __uint_as_float(u.y & 0xffff0000u);
  f[4] = __uint_as_float(u.z << 16); f[5] = __uint_as_float(u.z & 0xffff0000u);
  f[6] = __uint_as_float(u.w << 16); f[7] = __uint_as_float(u.w & 0xffff0000u);
}

__device__ __forceinline__ unsigned short bfbits(float f) {
  bf16 b = __float2bfloat16(f);
  return *(unsigned short*)&b;
}

__device__ __forceinline__ unsigned packh2(float a, float b) {
  union { unsigned u; __half2 h; } z;
  z.h = __floats2half2_rn(a, b);
  return z.u;
}

// Per-block dtype detection (bf16 vs fp32 inputs) — only k_build pays this
// (256 samples; bf16 scores ~256, fp32 ~51 — wide margin); publishes flag.
__device__ __forceinline__ int detect_bf(const unsigned short* xr, int tid, int nt) {
  __shared__ int s_cnt;
  if (tid == 0) s_cnt = 0;
  __syncthreads();
  int sane = 0;
  for (int i = tid; i < 256; i += nt) {
    int e = (xr[2 * i] >> 7) & 0xFF;
    sane += (e >= 100 && e <= 150) ? 1 : 0;
  }
  if (sane) atomicAdd(&s_cnt, sane);
  __syncthreads();
  return s_cnt > 180;
}

// Kernel 1: h = x @ w_gat (bf16 out); as_/ad_ logit halves; + fused ELL
// scatter; + publish dtype flag. 16 nodes/block (champion config —
// 32/block regressed in R20: doubles the edge-scatter trip count).
__global__ __launch_bounds__(256) void k_build(
    const void* __restrict__ x, const void* __restrict__ w,
    const void* __restrict__ asrc, const void* __restrict__ adst,
    const int* __restrict__ esrc, const int* __restrict__ edst, int E,
    int* __restrict__ cur, int* __restrict__ ell,
    bf16* __restrict__ h, float* __restrict__ as_, float* __restrict__ ad_,
    int* __restrict__ flagp)
{
  const int tid = threadIdx.x, lane = tid & 63, wid = tid >> 6;
  const int bf = detect_bf((const unsigned short*)x, tid, 256);
  if (tid == 0 && blockIdx.x == 0) *flagp = bf;
  __shared__ float wl[HD * HD];
  __shared__ float xr[4][HD];
  {
    for (int e = blockIdx.x * 256 + tid; e < E; e += gridDim.x * 256) {
      int d = edst[e];
      int k = atomicAdd(&cur[d], 1);
      if (k < DEGMAX) ell[d * DEGMAX + k] = esrc[e];
    }
  }
  for (int i = tid; i < HD * HD; i += 256) wl[i] = ldf(w, i, bf);
  const float av = ldf(asrc, lane, bf), dv_ = ldf(adst, lane, bf);
  __syncthreads();
#pragma unroll
  for (int r = 0; r < 4; ++r) {
    const int node = blockIdx.x * 16 + r * 4 + wid;
    xr[wid][lane] = ldf(x, node * HD + lane, bf);   // wave-local slot
    float hj = 0.f;
#pragma unroll
    for (int i = 0; i < HD; ++i) hj = fmaf(xr[wid][i], wl[i * HD + lane], hj);
    float pa = wave_sum(hj * av);
    float pd = wave_sum(hj * dv_);
    h[node * HD + lane] = __float2bfloat16(hj);
    if (lane == 0) { as_[node] = pa; ad_[node] = pd; }
  }
}

// Kernel 2: wave-per-node GAT gather (ELL) + bias + relu + residual + LN1 -> x1
// Batch-8 software pipeline: 8 independent neighbor loads in flight (MLP 8).
__global__ __launch_bounds__(256) void k_gather(
    const void* __restrict__ x, const int* __restrict__ cur,
    const int* __restrict__ ell, const float* __restrict__ as_,
    const float* __restrict__ ad_, const bf16* __restrict__ h,
    const void* __restrict__ bg, const void* __restrict__ g1,
    const void* __restrict__ b1, const int* __restrict__ dflag,
    bf16* __restrict__ x1)
{
  const int tid = threadIdx.x, lane = tid & 63, wid = tid >> 6;
  const int bf = *dflag;
  const int n = blockIdx.x * 4 + wid;
  const float adn = ad_[n];
  float e0 = as_[n] + adn;
  e0 = e0 > 0.f ? e0 : 0.2f * e0;
  float den = __expf(fminf(e0, 30.f));
  float num = den * b2f(h[n * HD + lane]);
  const int deg = min(cur[n], DEGMAX);
  const int* row = ell + n * DEGMAX;
  int i = 0;
  for (; i + 8 <= deg; i += 8) {
    int s[8];
#pragma unroll
    for (int k = 0; k < 8; ++k) s[k] = row[i + k];
    float a[8], hh[8];
#pragma unroll
    for (int k = 0; k < 8; ++k) a[k] = as_[s[k]];
#pragma unroll
    for (int k = 0; k < 8; ++k) hh[k] = b2f(h[s[k] * HD + lane]);
#pragma unroll
    for (int k = 0; k < 8; ++k) {
      float e = a[k] + adn;
      e = e > 0.f ? e : 0.2f * e;
      float p = __expf(fminf(e, 30.f));
      den += p;
      num = fmaf(p, hh[k], num);
    }
  }
  for (; i + 4 <= deg; i += 4) {
    int s0 = row[i], s1 = row[i + 1], s2 = row[i + 2], s3 = row[i + 3];
    float a0 = as_[s0], a1 = as_[s1], a2 = as_[s2], a3 = as_[s3];
    float h0 = b2f(h[s0 * HD + lane]), h1 = b2f(h[s1 * HD + lane]);
    float h2 = b2f(h[s2 * HD + lane]), h3 = b2f(h[s3 * HD + lane]);
    float e_0 = a0 + adn; e_0 = e_0 > 0.f ? e_0 : 0.2f * e_0;
    float e_1 = a1 + adn; e_1 = e_1 > 0.f ? e_1 : 0.2f * e_1;
    float e_2 = a2 + adn; e_2 = e_2 > 0.f ? e_2 : 0.2f * e_2;
    float e_3 = a3 + adn; e_3 = e_3 > 0.f ? e_3 : 0.2f * e_3;
    float p0 = __expf(fminf(e_0, 30.f)), p1 = __expf(fminf(e_1, 30.f));
    float p2 = __expf(fminf(e_2, 30.f)), p3 = __expf(fminf(e_3, 30.f));
    den += p0 + p1 + p2 + p3;
    num = fmaf(p0, h0, num); num = fmaf(p1, h1, num);
    num = fmaf(p2, h2, num); num = fmaf(p3, h3, num);
  }
  for (; i < deg; ++i) {
    int s = row[i];
    float e = as_[s] + adn;
    e = e > 0.f ? e : 0.2f * e;
    float p = __expf(fminf(e, 30.f));
    den += p;
    num = fmaf(p, b2f(h[s * HD + lane]), num);
  }
  float v = num / (den + 1e-16f) + ldf(bg, lane, bf);
  v = fmaxf(v, 0.f) + ldf(x, n * HD + lane, bf);
  float mu = wave_sum(v) * (1.f / 64.f);
  float dv = v - mu;
  float var = wave_sum(dv * dv) * (1.f / 64.f);
  float r = rsqrtf(var + 1e-5f);
  x1[n * HD + lane] =
      __float2bfloat16(dv * r * ldf(g1, lane, bf) + ldf(b1, lane, bf));
}

// Kernel 3: split-KV fused QKV + dense attention, 512 threads.
// R29: R28 algorithm (f16-packed K/V -> 2 ds_read_b128/iter; dot2 scores;
// pk_fma PV; ~52-reg live state) re-expressed with mainstream hip_fp16
// intrinsics (__floats2half2_rn / __hfma2 / __low2float) after two
// container failures on the raw _Float16 ext-vector version — hedge
// against a toolchain trigger while keeping the experiment identical.
// Post-mortem R27: allocator refuses >64 VGPR at 512 threads (52/64/56
// across R24-R27); f32 design's ~100-reg live state was serviced by
// AGPR-stash VALU traffic, pinning 54us at VALUBusy 62%. Fix: shrink the
// state to genuinely fit and halve both LDS and VALU instruction counts.
__global__ __launch_bounds__(512, 4) void k_attn13(
    const bf16* __restrict__ x1,
    const void* __restrict__ wq, const void* __restrict__ bq,
    const void* __restrict__ wk, const void* __restrict__ bk,
    const void* __restrict__ wv, const void* __restrict__ bv,
    const int* __restrict__ dflag,
    bf16* __restrict__ num_t, float* __restrict__ den_t)
{
  const int t = threadIdx.x;
  const int bf = *dflag;
  __shared__ unsigned KV[4 * KCH];   // 8.3 KB (f16-packed K|V rows)
  __shared__ float Wl[3][HD][DH];    // 6 KB
  __shared__ float bl[3][DH];
  const int bid = blockIdx.x;
  const int g = bid >> 4, hd = (bid >> 1) & 7, half = bid & 1;
  {
    // 512 threads, 512 (i,j) cells per matrix: one cell each.
    int i = t >> 3, j = t & 7;
    int col = hd * DH + j;
    Wl[0][i][j] = ldf(wq, i * HD + col, bf);
    Wl[1][i][j] = ldf(wk, i * HD + col, bf);
    Wl[2][i][j] = ldf(wv, i * HD + col, bf);
    if (t < DH) {
      bl[0][t] = ldf(bq, hd * DH + t, bf);
      bl[1][t] = ldf(bk, hd * DH + t, bf);
      bl[2][t] = ldf(bv, hd * DH + t, bf);
    }
  }
  __syncthreads();
  // qscale = (1/sqrt(8)) * log2(e): softmax via exp2.
  const float qscale = 0.3535533905932738f * 1.4426950408889634f;
  {
    // ---- K (waves 0-3) or V (waves 4-7) projection for local row t&255 ----
    const int r = t & 255;
    const int m = (t < 256) ? 1 : 2;   // wave-uniform: no divergence
    const uint4* xk4 = (const uint4*)(x1 + (size_t)(g * NPG + half * 256 + r) * HD);
    float acc[DH];
#pragma unroll
    for (int j = 0; j < DH; ++j) acc[j] = bl[m][j];
#pragma unroll
    for (int blk = 0; blk < 8; ++blk) {
      float xv[8];
      unpack8(xk4[blk], xv);
      const int ib = blk * 8;
#pragma unroll
      for (int ii = 0; ii < 8; ++ii)
#pragma unroll
        for (int j = 0; j < DH; ++j)
          acc[j] = fmaf(xv[ii], Wl[m][ib + ii][j], acc[j]);
    }
    // pack 8 f32 -> 4 f16x2 words, one 16B store (K at +0, V at +4 words)
    uint4 pkv;
    pkv.x = packh2(acc[0], acc[1]);
    pkv.y = packh2(acc[2], acc[3]);
    pkv.z = packh2(acc[4], acc[5]);
    pkv.w = packh2(acc[6], acc[7]);
    unsigned* kvrow = KV + (r >> 6) * KCH + (r & 63) * 8 + ((t < 256) ? 0 : 4);
    *(uint4*)kvrow = pkv;
  }
  // ---- Q projection: row t, registers only; scale; pack to f16 pairs ----
  int qp[4];
  {
    const uint4* xa4 = (const uint4*)(x1 + (size_t)(g * NPG + t) * HD);
    float qa[DH];
#pragma unroll
    for (int j = 0; j < DH; ++j) qa[j] = bl[0][j];
#pragma unroll
    for (int blk = 0; blk < 8; ++blk) {
      float xv[8];
      unpack8(xa4[blk], xv);
      const int ib = blk * 8;
#pragma unroll
      for (int ii = 0; ii < 8; ++ii)
#pragma unroll
        for (int j = 0; j < DH; ++j)
          qa[j] = fmaf(xv[ii], Wl[0][ib + ii][j], qa[j]);
    }
#pragma unroll
    for (int j = 0; j < 4; ++j)
      qp[j] = (int)packh2(qa[2 * j] * qscale, qa[2 * j + 1] * qscale);
  }
  __syncthreads();   // KV LDS ready
  // ---- redistribute packed Q inside each 4-lane cluster (16 shfl) ----
  const int lane = t & 63;
  const int base = lane & ~3;
  unsigned qw[4][4];
#pragma unroll
  for (int i = 0; i < 4; ++i)
#pragma unroll
    for (int j = 0; j < 4; ++j)
      qw[i][j] = (unsigned)__shfl(qp[j], base + i, 64);
  // ---- attention: 4 queries per thread over a 64-row chunk ----
  const int qg = t >> 2, c = t & 3;   // qg in [0,128): queries qg*4 .. qg*4+3
  float den[4];
  __half2 num2[4][4];
  const __half2 zero2 = __floats2half2_rn(0.f, 0.f);
#pragma unroll
  for (int i = 0; i < 4; ++i) {
    den[i] = 0.f;
#pragma unroll
    for (int j = 0; j < 4; ++j) num2[i][j] = zero2;
  }
  const unsigned* kvc = KV + c * KCH;
#pragma unroll 4
  for (int jj = 0; jj < 64; ++jj) {
    const uint4* kvp = (const uint4*)(kvc + jj * 8);
    uint4 ku = kvp[0], vu = kvp[1];
    __half2 v2[4];
    { union { unsigned u; __half2 h; } z;
      z.u = vu.x; v2[0] = z.h; z.u = vu.y; v2[1] = z.h;
      z.u = vu.z; v2[2] = z.h; z.u = vu.w; v2[3] = z.h; }
#pragma unroll
    for (int i = 0; i < 4; ++i) {
      float s = fdot2u(qw[i][0], ku.x, 0.f);
      s = fdot2u(qw[i][1], ku.y, s);
      s = fdot2u(qw[i][2], ku.z, s);
      s = fdot2u(qw[i][3], ku.w, s);
      float p = EXP2F(s);   // q pre-scaled by log2e/sqrt(DH)
      den[i] += p;
      __half2 p2 = __float2half2_rn(p);
      num2[i][0] = __hfma2(p2, v2[0], num2[i][0]);
      num2[i][1] = __hfma2(p2, v2[1], num2[i][1]);
      num2[i][2] = __hfma2(p2, v2[2], num2[i][2]);
      num2[i][3] = __hfma2(p2, v2[3], num2[i][3]);
    }
  }
  // unpack f16 chunk-partials to f32 for the merge
  float num[4][DH];
#pragma unroll
  for (int i = 0; i < 4; ++i)
#pragma unroll
    for (int j = 0; j < 4; ++j) {
      num[i][2 * j]     = __low2float(num2[i][j]);
      num[i][2 * j + 1] = __high2float(num2[i][j]);
    }
  // merge the 4 chunk-lanes (butterfly over c bits 1,2)
#pragma unroll
  for (int st = 1; st <= 2; st <<= 1) {
#pragma unroll
    for (int i = 0; i < 4; ++i) {
      den[i] += __shfl_xor(den[i], st);
#pragma unroll
      for (int j = 0; j < DH; ++j) num[i][j] += __shfl_xor(num[i][j], st);
    }
  }
  // lane c writes query qg*4+c UNNORMALIZED (one query per lane).
  const int plane = half * 8 + hd;
  float dsel = 0.f, rsel[DH];
#pragma unroll
  for (int j = 0; j < DH; ++j) rsel[j] = 0.f;
#pragma unroll
  for (int i = 0; i < 4; ++i) {
    if (c == i) {
      dsel = den[i];
#pragma unroll
      for (int j = 0; j < DH; ++j) rsel[j] = num[i][j];
    }
  }
  const int qrow = qg * 4 + c;
  union { uint4 u4; unsigned short us[8]; } pk;
#pragma unroll
  for (int j = 0; j < DH; ++j) pk.us[j] = bfbits(rsel[j]);
  *(uint4*)(num_t + ((size_t)plane * NN + g * NPG + qrow) * 8) = pk.u4;
  den_t[(size_t)plane * NN + g * NPG + qrow] = dsel;
}

// Kernel 4: merge attn halves -> o; y = relu(o @ wo + bo);
// out = LN(x1 + y; g2, b2). 32 nodes/block (isolated de-confound of R20:
// halves the 16 KB wo-staging traffic; no atomics/grid-stride coupling).
__global__ __launch_bounds__(256) void k_out(
    const bf16* __restrict__ num_t, const float* __restrict__ den_t,
    const bf16* __restrict__ x1,
    const void* __restrict__ wo, const void* __restrict__ bo,
    const void* __restrict__ g2, const void* __restrict__ b2,
    const int* __restrict__ dflag, void* __restrict__ out)
{
  const int tid = threadIdx.x, lane = tid & 63, wid = tid >> 6;
  const int bf = *dflag;
  __shared__ float wl[HD * HD];
  __shared__ float orow[4][HD];
  for (int i = tid; i < HD * HD; i += 256) wl[i] = ldf(wo, i, bf);
  const float bov = ldf(bo, lane, bf);
  const float g2v = ldf(g2, lane, bf);
  const float b2v = ldf(b2, lane, bf);
  const int hdp = lane >> 3, jp = lane & 7;
  __syncthreads();
#pragma unroll
  for (int r = 0; r < 8; ++r) {
    const int node = blockIdx.x * 32 + r * 4 + wid;
    {
      float nm = b2f(num_t[((size_t)hdp * NN + node) * 8 + jp]) +
                 b2f(num_t[((size_t)(8 + hdp) * NN + node) * 8 + jp]);
      float dn = den_t[(size_t)hdp * NN + node] +
                 den_t[(size_t)(8 + hdp) * NN + node];
      orow[wid][lane] = nm / dn;   // wave-local slot
    }
    float y = bov;
#pragma unroll
    for (int i = 0; i < HD; ++i) y = fmaf(orow[wid][i], wl[i * HD + lane], y);
    float tt = b2f(x1[node * HD + lane]) + fmaxf(y, 0.f);
    float mu = wave_sum(tt) * (1.f / 64.f);
    float dv = tt - mu;
    float var = wave_sum(dv * dv) * (1.f / 64.f);
    float rr = rsqrtf(var + 1e-5f);
    float res = dv * rr * g2v + b2v;
    if (bf) ((bf16*)out)[node * HD + lane] = __float2bfloat16(res);
    else    ((float*)out)[node * HD + lane] = res;
  }
}

extern "C" void kernel_launch(void* const* d_in, const int* in_sizes, int n_in,
                              void* d_out, int out_size, void* d_ws, size_t ws_size,
                              hipStream_t stream)
{
  const void* x    = d_in[0];
  const void* wgat = d_in[1];
  const void* asrc = d_in[2];
  const void* adst = d_in[3];
  const void* bgat = d_in[4];
  const void* g1   = d_in[5];
  const void* b1   = d_in[6];
  const void* wq   = d_in[7];
  const void* bq   = d_in[8];
  const void* wk   = d_in[9];
  const void* bk   = d_in[10];
  const void* wv   = d_in[11];
  const void* bv   = d_in[12];
  const void* wo   = d_in[13];
  const void* bo   = d_in[14];
  const void* g2   = d_in[15];
  const void* b2   = d_in[16];
  const int*  ei   = (const int*)d_in[17];
  const int E = in_sizes[17] / 2;
  const int* esrc = ei;
  const int* edst = ei + E;

  // Workspace (~7.2 MiB):
  //   [0, 2M):      bf16 x1
  //   [2M, 4.62M):  ell (NN*DEGMAX int)    } dead after k_gather;
  //   [4.62M,6.62M):bf16 h                 } k_attn13 overwrites:
  //   [2M, 6M):     bf16 num_t (16 planes * NN * 8)
  //   [6M, 7M):     f32 den_t (16 planes * NN)
  //   [7M, ...):    as_, ad_ (NN f32 each), cur (NN int), flag
  char* W = (char*)d_ws;
  bf16*  x1b   = (bf16*)W;
  int*   ell   = (int*)(W + (size_t)(2 << 20));
  bf16*  hb    = (bf16*)(W + (size_t)(2 << 20) + (size_t)NN * DEGMAX * 4);
  bf16*  num_t = (bf16*)(W + (size_t)(2 << 20));
  float* den_t = (float*)(W + (size_t)(6 << 20));
  float* as_   = (float*)(W + (size_t)(7 << 20));
  float* ad_   = as_ + NN;
  int*   cur   = (int*)(ad_ + NN);
  int*   flag  = cur + NN;

  hipMemsetAsync(cur, 0, NN * sizeof(int), stream);
  k_build  <<<NN / 16, 256, 0, stream>>>(x, wgat, asrc, adst, esrc, edst, E,
                                         cur, ell, hb, as_, ad_, flag);
  k_gather <<<NN / 4, 256, 0, stream>>>(x, cur, ell, as_, ad_, hb,
                                        bgat, g1, b1, flag, x1b);
  k_attn13 <<<BG * NHEADS * 2, 512, 0, stream>>>(x1b, wq, bq, wk, bk, wv, bv,
                                                 flag, num_t, den_t);
  k_out    <<<NN / 32, 256, 0, stream>>>(num_t, den_t, x1b, wo, bo, g2, b2,
                                         flag, d_out);
}

// Round 9
// 178.667 us; speedup vs baseline: 1.1133x; 1.0843x over previous
//
#include <hip/hip_runtime.h>
#include <hip/hip_bf16.h>
#include <hip/hip_fp16.h>

// Problem constants (from reference)
#define NN     16384   // nodes
#define HD     64      // hidden dim
#define BG     32      // graphs
#define NPG    512     // nodes per graph
#define NHEADS 8
#define DH     8
#define DEGMAX 40      // ELL width; deg ~ Poisson(16), P(>40) ~ 3e-8/node

// R30 MFMA attn LDS geometry (f16):
//   Qs[512][12], Ks[256][12]: row stride 12 f16 = 24B -> b64 fragment reads
//   8B-aligned; bank stride 6 -> only 2-way aliasing (free, m136).
//   Vt[8][264]: V transposed; row stride 528B -> the 8 dh-rows hit banks
//   {0,4,8,...,28}; b64 frag reads conflict-free; lanes 8-31 broadcast.
#define QS_STR 12
#define KS_STR 12
#define VT_STR 264

typedef __hip_bfloat16 bf16;
typedef _Float16 v4h __attribute__((ext_vector_type(4)));
typedef float v16f __attribute__((ext_vector_type(16)));

#if defined(__has_builtin)
#if __has_builtin(__builtin_amdgcn_exp2f)
#define EXP2F(x) __builtin_amdgcn_exp2f(x)
#else
#define EXP2F(x) exp2f(x)
#endif
#else
#define EXP2F(x) exp2f(x)
#endif

__device__ __forceinline__ float b2f(bf16 v) { return __bfloat162float(v); }

// Flag-steered input load: bf=1 -> buffer is bf16, bf=0 -> fp32.
__device__ __forceinline__ float ldf(const void* p, int i, int bf) {
  return bf ? __bfloat162float(((const bf16*)p)[i]) : ((const float*)p)[i];
}

__device__ __forceinline__ float wave_sum(float v) {
#pragma unroll
  for (int off = 32; off > 0; off >>= 1) v += __shfl_xor(v, off);
  return v;
}

__device__ __forceinline__ void unpack8(uint4 u, float* f) {
  f[0] = __uint_as_float(u.x << 16); f[1] = __uint_as_float(u.x & 0xffff0000u);
  f[2] = __uint_as_float(u.y << 16); f[3] = __uint_as_float(u.y & 0xffff0000u);
  f[4] = __uint_as_float(u.z << 16); f[5] = __uint_as_float(u.z & 0xffff0000u);
  f[6] = __uint_as_float(u.w << 16); f[7] = __uint_as_float(u.w & 0xffff0000u);
}

__device__ __forceinline__ unsigned short bfbits(float f) {
  bf16 b = __float2bfloat16(f);
  return *(unsigned short*)&b;
}

__device__ __forceinline__ unsigned packh2(float a, float b) {
  union { unsigned u; __half2 h; } z;
  z.h = __floats2half2_rn(a, b);
  return z.u;
}

// Per-block dtype detection (bf16 vs fp32 inputs) — only k_build pays this
// (256 samples; bf16 scores ~256, fp32 ~51 — wide margin); publishes flag.
__device__ __forceinline__ int detect_bf(const unsigned short* xr, int tid, int nt) {
  __shared__ int s_cnt;
  if (tid == 0) s_cnt = 0;
  __syncthreads();
  int sane = 0;
  for (int i = tid; i < 256; i += nt) {
    int e = (xr[2 * i] >> 7) & 0xFF;
    sane += (e >= 100 && e <= 150) ? 1 : 0;
  }
  if (sane) atomicAdd(&s_cnt, sane);
  __syncthreads();
  return s_cnt > 180;
}

// Kernel 1: h = x @ w_gat (bf16 out); as_/ad_ logit halves; + fused ELL
// scatter; + publish dtype flag. 16 nodes/block (champion config —
// 32/block regressed in R20: doubles the edge-scatter trip count).
__global__ __launch_bounds__(256) void k_build(
    const void* __restrict__ x, const void* __restrict__ w,
    const void* __restrict__ asrc, const void* __restrict__ adst,
    const int* __restrict__ esrc, const int* __restrict__ edst, int E,
    int* __restrict__ cur, int* __restrict__ ell,
    bf16* __restrict__ h, float* __restrict__ as_, float* __restrict__ ad_,
    int* __restrict__ flagp)
{
  const int tid = threadIdx.x, lane = tid & 63, wid = tid >> 6;
  const int bf = detect_bf((const unsigned short*)x, tid, 256);
  if (tid == 0 && blockIdx.x == 0) *flagp = bf;
  __shared__ float wl[HD * HD];
  __shared__ float xr[4][HD];
  {
    for (int e = blockIdx.x * 256 + tid; e < E; e += gridDim.x * 256) {
      int d = edst[e];
      int k = atomicAdd(&cur[d], 1);
      if (k < DEGMAX) ell[d * DEGMAX + k] = esrc[e];
    }
  }
  for (int i = tid; i < HD * HD; i += 256) wl[i] = ldf(w, i, bf);
  const float av = ldf(asrc, lane, bf), dv_ = ldf(adst, lane, bf);
  __syncthreads();
#pragma unroll
  for (int r = 0; r < 4; ++r) {
    const int node = blockIdx.x * 16 + r * 4 + wid;
    xr[wid][lane] = ldf(x, node * HD + lane, bf);   // wave-local slot
    float hj = 0.f;
#pragma unroll
    for (int i = 0; i < HD; ++i) hj = fmaf(xr[wid][i], wl[i * HD + lane], hj);
    float pa = wave_sum(hj * av);
    float pd = wave_sum(hj * dv_);
    h[node * HD + lane] = __float2bfloat16(hj);
    if (lane == 0) { as_[node] = pa; ad_[node] = pd; }
  }
}

// Kernel 2: wave-per-node GAT gather (ELL) + bias + relu + residual + LN1 -> x1
// Batch-8 software pipeline: 8 independent neighbor loads in flight (MLP 8).
__global__ __launch_bounds__(256) void k_gather(
    const void* __restrict__ x, const int* __restrict__ cur,
    const int* __restrict__ ell, const float* __restrict__ as_,
    const float* __restrict__ ad_, const bf16* __restrict__ h,
    const void* __restrict__ bg, const void* __restrict__ g1,
    const void* __restrict__ b1, const int* __restrict__ dflag,
    bf16* __restrict__ x1)
{
  const int tid = threadIdx.x, lane = tid & 63, wid = tid >> 6;
  const int bf = *dflag;
  const int n = blockIdx.x * 4 + wid;
  const float adn = ad_[n];
  float e0 = as_[n] + adn;
  e0 = e0 > 0.f ? e0 : 0.2f * e0;
  float den = __expf(fminf(e0, 30.f));
  float num = den * b2f(h[n * HD + lane]);
  const int deg = min(cur[n], DEGMAX);
  const int* row = ell + n * DEGMAX;
  int i = 0;
  for (; i + 8 <= deg; i += 8) {
    int s[8];
#pragma unroll
    for (int k = 0; k < 8; ++k) s[k] = row[i + k];
    float a[8], hh[8];
#pragma unroll
    for (int k = 0; k < 8; ++k) a[k] = as_[s[k]];
#pragma unroll
    for (int k = 0; k < 8; ++k) hh[k] = b2f(h[s[k] * HD + lane]);
#pragma unroll
    for (int k = 0; k < 8; ++k) {
      float e = a[k] + adn;
      e = e > 0.f ? e : 0.2f * e;
      float p = __expf(fminf(e, 30.f));
      den += p;
      num = fmaf(p, hh[k], num);
    }
  }
  for (; i + 4 <= deg; i += 4) {
    int s0 = row[i], s1 = row[i + 1], s2 = row[i + 2], s3 = row[i + 3];
    float a0 = as_[s0], a1 = as_[s1], a2 = as_[s2], a3 = as_[s3];
    float h0 = b2f(h[s0 * HD + lane]), h1 = b2f(h[s1 * HD + lane]);
    float h2 = b2f(h[s2 * HD + lane]), h3 = b2f(h[s3 * HD + lane]);
    float e_0 = a0 + adn; e_0 = e_0 > 0.f ? e_0 : 0.2f * e_0;
    float e_1 = a1 + adn; e_1 = e_1 > 0.f ? e_1 : 0.2f * e_1;
    float e_2 = a2 + adn; e_2 = e_2 > 0.f ? e_2 : 0.2f * e_2;
    float e_3 = a3 + adn; e_3 = e_3 > 0.f ? e_3 : 0.2f * e_3;
    float p0 = __expf(fminf(e_0, 30.f)), p1 = __expf(fminf(e_1, 30.f));
    float p2 = __expf(fminf(e_2, 30.f)), p3 = __expf(fminf(e_3, 30.f));
    den += p0 + p1 + p2 + p3;
    num = fmaf(p0, h0, num); num = fmaf(p1, h1, num);
    num = fmaf(p2, h2, num); num = fmaf(p3, h3, num);
  }
  for (; i < deg; ++i) {
    int s = row[i];
    float e = as_[s] + adn;
    e = e > 0.f ? e : 0.2f * e;
    float p = __expf(fminf(e, 30.f));
    den += p;
    num = fmaf(p, b2f(h[s * HD + lane]), num);
  }
  float v = num / (den + 1e-16f) + ldf(bg, lane, bf);
  v = fmaxf(v, 0.f) + ldf(x, n * HD + lane, bf);
  float mu = wave_sum(v) * (1.f / 64.f);
  float dv = v - mu;
  float var = wave_sum(dv * dv) * (1.f / 64.f);
  float r = rsqrtf(var + 1e-5f);
  x1[n * HD + lane] =
      __float2bfloat16(dv * r * ldf(g1, lane, bf) + ldf(b1, lane, bf));
}

// Kernel 3: split-KV fused QKV + dense attention, 512 threads, MFMA core.
// R30: five structures (R24-R29) pinned at 50-54us with MfmaUtil=0 while
// VALU count, LDS count, occupancy, and registers were each halved
// independently -> scalar dot-product attention is dependency-bound on
// the VALU/LDS pipes. Move QK^T and PV to the idle matrix pipe:
//   S^T-tile = mfma_32x32x8_f16(A=K, B=Q^T)  (K=8 == DH, zero padding);
//   C layout (m74/m101-verified): lane=query col, key=(reg&3)+8(reg>>2)
//   +4(lane>>5) -> C-regs [4g..4g+3], exp2'd+packed, ARE the A-fragment
//   of the 8-key PV step g: O += mfma(A=P-step, B=V) -- no cross-lane
//   data movement between QK^T and PV; f32 accumulation (better than
//   R29's f16). den = per-lane sum of exp'd C-regs + one shfl_xor(32).
// Projections stay scalar this round (isolate one variable).
// launch_bounds(512,2): 128-VGPR budget; grid (512 blk) still 4 w/SIMD.
__global__ __launch_bounds__(512, 2) void k_attn13(
    const bf16* __restrict__ x1,
    const void* __restrict__ wq, const void* __restrict__ bq,
    const void* __restrict__ wk, const void* __restrict__ bk,
    const void* __restrict__ wv, const void* __restrict__ bv,
    const int* __restrict__ dflag,
    bf16* __restrict__ num_t, float* __restrict__ den_t)
{
  const int t = threadIdx.x;
  const int bf = *dflag;
  __shared__ _Float16 Qs[NPG * QS_STR];   // 12 KB
  __shared__ _Float16 Ks[256 * KS_STR];   // 6 KB
  __shared__ _Float16 Vt[DH * VT_STR];    // 4.1 KB (V transposed)
  __shared__ float Wl[3][HD][DH];         // 6 KB
  __shared__ float bl[3][DH];
  const int bid = blockIdx.x;
  const int g = bid >> 4, hd = (bid >> 1) & 7, half = bid & 1;
  {
    // 512 threads, 512 (i,j) cells per matrix: one cell each.
    int i = t >> 3, j = t & 7;
    int col = hd * DH + j;
    Wl[0][i][j] = ldf(wq, i * HD + col, bf);
    Wl[1][i][j] = ldf(wk, i * HD + col, bf);
    Wl[2][i][j] = ldf(wv, i * HD + col, bf);
    if (t < DH) {
      bl[0][t] = ldf(bq, hd * DH + t, bf);
      bl[1][t] = ldf(bk, hd * DH + t, bf);
      bl[2][t] = ldf(bv, hd * DH + t, bf);
    }
  }
  __syncthreads();
  // qscale = (1/sqrt(8)) * log2(e): softmax via exp2 (folded into Q).
  const float qscale = 0.3535533905932738f * 1.4426950408889634f;
  {
    // ---- K (waves 0-3) or V (waves 4-7) projection for local row t&255 ----
    const int r = t & 255;
    const int m = (t < 256) ? 1 : 2;   // wave-uniform: no divergence
    const uint4* xk4 = (const uint4*)(x1 + (size_t)(g * NPG + half * 256 + r) * HD);
    float acc[DH];
#pragma unroll
    for (int j = 0; j < DH; ++j) acc[j] = bl[m][j];
#pragma unroll
    for (int blk = 0; blk < 8; ++blk) {
      float xv[8];
      unpack8(xk4[blk], xv);
      const int ib = blk * 8;
#pragma unroll
      for (int ii = 0; ii < 8; ++ii)
#pragma unroll
        for (int j = 0; j < DH; ++j)
          acc[j] = fmaf(xv[ii], Wl[m][ib + ii][j], acc[j]);
    }
    if (t < 256) {
      // K row r: 8 f16 packed, two 8B stores (24B row stride).
      unsigned w0 = packh2(acc[0], acc[1]), w1 = packh2(acc[2], acc[3]);
      unsigned w2 = packh2(acc[4], acc[5]), w3 = packh2(acc[6], acc[7]);
      *(uint2*)(Ks + r * KS_STR) = make_uint2(w0, w1);
      *(uint2*)(Ks + r * KS_STR + 4) = make_uint2(w2, w3);
    } else {
      // V row r transposed: 8 scalar f16 stores (2 lanes/bank = free).
#pragma unroll
      for (int j = 0; j < DH; ++j) Vt[j * VT_STR + r] = (_Float16)acc[j];
    }
  }
  {
    // ---- Q projection: row t -> Qs (pre-scaled by qscale) ----
    const uint4* xa4 = (const uint4*)(x1 + (size_t)(g * NPG + t) * HD);
    float qa[DH];
#pragma unroll
    for (int j = 0; j < DH; ++j) qa[j] = bl[0][j];
#pragma unroll
    for (int blk = 0; blk < 8; ++blk) {
      float xv[8];
      unpack8(xa4[blk], xv);
      const int ib = blk * 8;
#pragma unroll
      for (int ii = 0; ii < 8; ++ii)
#pragma unroll
        for (int j = 0; j < DH; ++j)
          qa[j] = fmaf(xv[ii], Wl[0][ib + ii][j], qa[j]);
    }
    unsigned w0 = packh2(qa[0] * qscale, qa[1] * qscale);
    unsigned w1 = packh2(qa[2] * qscale, qa[3] * qscale);
    unsigned w2 = packh2(qa[4] * qscale, qa[5] * qscale);
    unsigned w3 = packh2(qa[6] * qscale, qa[7] * qscale);
    *(uint2*)(Qs + t * QS_STR) = make_uint2(w0, w1);
    *(uint2*)(Qs + t * QS_STR + 4) = make_uint2(w2, w3);
  }
  __syncthreads();   // Qs/Ks/Vt ready
  // ---- MFMA attention: 8 waves x 2 query-tiles of 32 ----
  const int lane = t & 63, wid = t >> 6;
  const int ln = lane & 31, hh = lane >> 5;
  const int plane = half * 8 + hd;
  const size_t obase = (size_t)plane * NN + (size_t)g * NPG;
  v16f zf;
#pragma unroll
  for (int i = 0; i < 16; ++i) zf[i] = 0.f;
#pragma unroll
  for (int qt = 0; qt < 2; ++qt) {
    const int qbase = (wid * 2 + qt) * 32;
    // B-fragment: Q^T -> lane ln holds query qbase+ln, dh 4*hh..+3.
    v4h qf = *(const v4h*)(Qs + (qbase + ln) * QS_STR + 4 * hh);
    v16f oacc = zf;
    float den = 0.f;
#pragma unroll
    for (int kt = 0; kt < 8; ++kt) {
      // A-fragment: K -> lane ln holds key kt*32+ln, dh 4*hh..+3.
      v4h kf = *(const v4h*)(Ks + (kt * 32 + ln) * KS_STR + 4 * hh);
      v16f s = __builtin_amdgcn_mfma_f32_32x32x8f16(kf, qf, zf, 0, 0, 0);
#pragma unroll
      for (int g2 = 0; g2 < 4; ++g2) {
        float e0 = EXP2F(s[4 * g2 + 0]);
        float e1 = EXP2F(s[4 * g2 + 1]);
        float e2 = EXP2F(s[4 * g2 + 2]);
        float e3 = EXP2F(s[4 * g2 + 3]);
        den += (e0 + e1) + (e2 + e3);
        union { unsigned u[2]; v4h v; } pu;
        pu.u[0] = packh2(e0, e1);
        pu.u[1] = packh2(e2, e3);
        // B-fragment: V -> lane ln holds dh col ln&7 (cols 8-31 dup,
        // outputs there unread), keys kt*32+g2*8+4*hh..+3.
        v4h vf = *(const v4h*)(Vt + (ln & 7) * VT_STR + kt * 32 + g2 * 8 + 4 * hh);
        oacc = __builtin_amdgcn_mfma_f32_32x32x8f16(pu.v, vf, oacc, 0, 0, 0);
      }
    }
    // den: lane halves hold complementary key sets of the same query.
    den += __shfl_xor(den, 32);
    if (lane < 32) den_t[obase + qbase + lane] = den;
    // O: C layout -> lane ln<8 holds dh=ln; query per reg & lane-half.
#pragma unroll
    for (int r = 0; r < 16; ++r) {
      const int q = qbase + (r & 3) + 8 * (r >> 2) + 4 * hh;
      if (ln < 8)
        num_t[(obase + q) * 8 + ln] = __float2bfloat16(oacc[r]);
    }
  }
}

// Kernel 4: merge attn halves -> o; y = relu(o @ wo + bo);
// out = LN(x1 + y; g2, b2). 32 nodes/block (isolated de-confound of R20:
// halves the 16 KB wo-staging traffic; no atomics/grid-stride coupling).
__global__ __launch_bounds__(256) void k_out(
    const bf16* __restrict__ num_t, const float* __restrict__ den_t,
    const bf16* __restrict__ x1,
    const void* __restrict__ wo, const void* __restrict__ bo,
    const void* __restrict__ g2, const void* __restrict__ b2,
    const int* __restrict__ dflag, void* __restrict__ out)
{
  const int tid = threadIdx.x, lane = tid & 63, wid = tid >> 6;
  const int bf = *dflag;
  __shared__ float wl[HD * HD];
  __shared__ float orow[4][HD];
  for (int i = tid; i < HD * HD; i += 256) wl[i] = ldf(wo, i, bf);
  const float bov = ldf(bo, lane, bf);
  const float g2v = ldf(g2, lane, bf);
  const float b2v = ldf(b2, lane, bf);
  const int hdp = lane >> 3, jp = lane & 7;
  __syncthreads();
#pragma unroll
  for (int r = 0; r < 8; ++r) {
    const int node = blockIdx.x * 32 + r * 4 + wid;
    {
      float nm = b2f(num_t[((size_t)hdp * NN + node) * 8 + jp]) +
                 b2f(num_t[((size_t)(8 + hdp) * NN + node) * 8 + jp]);
      float dn = den_t[(size_t)hdp * NN + node] +
                 den_t[(size_t)(8 + hdp) * NN + node];
      orow[wid][lane] = nm / dn;   // wave-local slot
    }
    float y = bov;
#pragma unroll
    for (int i = 0; i < HD; ++i) y = fmaf(orow[wid][i], wl[i * HD + lane], y);
    float tt = b2f(x1[node * HD + lane]) + fmaxf(y, 0.f);
    float mu = wave_sum(tt) * (1.f / 64.f);
    float dv = tt - mu;
    float var = wave_sum(dv * dv) * (1.f / 64.f);
    float rr = rsqrtf(var + 1e-5f);
    float res = dv * rr * g2v + b2v;
    if (bf) ((bf16*)out)[node * HD + lane] = __float2bfloat16(res);
    else    ((float*)out)[node * HD + lane] = res;
  }
}

extern "C" void kernel_launch(void* const* d_in, const int* in_sizes, int n_in,
                              void* d_out, int out_size, void* d_ws, size_t ws_size,
                              hipStream_t stream)
{
  const void* x    = d_in[0];
  const void* wgat = d_in[1];
  const void* asrc = d_in[2];
  const void* adst = d_in[3];
  const void* bgat = d_in[4];
  const void* g1   = d_in[5];
  const void* b1   = d_in[6];
  const void* wq   = d_in[7];
  const void* bq   = d_in[8];
  const void* wk   = d_in[9];
  const void* bk   = d_in[10];
  const void* wv   = d_in[11];
  const void* bv   = d_in[12];
  const void* wo   = d_in[13];
  const void* bo   = d_in[14];
  const void* g2   = d_in[15];
  const void* b2   = d_in[16];
  const int*  ei   = (const int*)d_in[17];
  const int E = in_sizes[17] / 2;
  const int* esrc = ei;
  const int* edst = ei + E;

  // Workspace (~7.2 MiB):
  //   [0, 2M):      bf16 x1
  //   [2M, 4.62M):  ell (NN*DEGMAX int)    } dead after k_gather;
  //   [4.62M,6.62M):bf16 h                 } k_attn13 overwrites:
  //   [2M, 6M):     bf16 num_t (16 planes * NN * 8)
  //   [6M, 7M):     f32 den_t (16 planes * NN)
  //   [7M, ...):    as_, ad_ (NN f32 each), cur (NN int), flag
  char* W = (char*)d_ws;
  bf16*  x1b   = (bf16*)W;
  int*   ell   = (int*)(W + (size_t)(2 << 20));
  bf16*  hb    = (bf16*)(W + (size_t)(2 << 20) + (size_t)NN * DEGMAX * 4);
  bf16*  num_t = (bf16*)(W + (size_t)(2 << 20));
  float* den_t = (float*)(W + (size_t)(6 << 20));
  float* as_   = (float*)(W + (size_t)(7 << 20));
  float* ad_   = as_ + NN;
  int*   cur   = (int*)(ad_ + NN);
  int*   flag  = cur + NN;

  hipMemsetAsync(cur, 0, NN * sizeof(int), stream);
  k_build  <<<NN / 16, 256, 0, stream>>>(x, wgat, asrc, adst, esrc, edst, E,
                                         cur, ell, hb, as_, ad_, flag);
  k_gather <<<NN / 4, 256, 0, stream>>>(x, cur, ell, as_, ad_, hb,
                                        bgat, g1, b1, flag, x1b);
  k_attn13 <<<BG * NHEADS * 2, 512, 0, stream>>>(x1b, wq, bq, wk, bk, wv, bv,
                                                 flag, num_t, den_t);
  k_out    <<<NN / 32, 256, 0, stream>>>(num_t, den_t, x1b, wo, bo, g2, b2,
                                         flag, d_out);
}